// Round 2
// 132.749 us; speedup vs baseline: 1.0146x; 1.0146x over previous
//
#include <hip/hip_runtime.h>
#include <hip/hip_bf16.h>
#include <math.h>

// ---- problem constants ----
#define BATCH 16
#define CIN   128
#define COUT  128
#define SS    3136          // 56*56
#define XT_ROW 8192         // shorts per padded row: 64 pcol * 128 ci
#define XT_PER_B (58*XT_ROW)
#define NKB   18

typedef __attribute__((ext_vector_type(8))) __bf16 bf16x8;
typedef __attribute__((ext_vector_type(4))) float  floatx4;

static __device__ __forceinline__ unsigned short f2bf(float f) {
  union { float f; unsigned u; } v; v.f = f;
  unsigned r = v.u + 0x7fffu + ((v.u >> 16) & 1u);   // RNE
  return (unsigned short)(r >> 16);
}
static __device__ __forceinline__ float bf2f(unsigned short u) {
  union { unsigned u; float f; } v; v.u = ((unsigned)u) << 16; return v.f;
}

static __device__ __forceinline__ float waveReduceSum(float v) {
  #pragma unroll
  for (int off = 32; off > 0; off >>= 1) v += __shfl_xor(v, off, 64);
  return v;
}

static __device__ __forceinline__ void load_lds16(const void* g, void* l) {
  __builtin_amdgcn_global_load_lds(
      (const __attribute__((address_space(1))) void*)g,
      (__attribute__((address_space(3))) void*)l, 16, 0, 0);
}

// LDS column-block swizzle: spreads banks across ci for transpose reads
static __device__ __forceinline__ int sswz(int ci) {
  return (ci ^ (ci >> 4)) & 15;
}

// K0: fused pad+transpose to NHWC bf16 + attention mask row + exp + per-row
// context partials. Wave-coalesced float4 global loads, b64 LDS writes,
// XOR-swizzled LDS tile (stride 64, 4-short blocks), pad-row early out.
// Logical sx[ci][col] lives at sx[ci*64 + ((col>>2 ^ sswz(ci))<<2) + (col&3)].
__global__ __launch_bounds__(256, 4)
void k0_padT(const float* __restrict__ x, const float* __restrict__ w_mask,
             const float* __restrict__ b_mask,
             unsigned short* __restrict__ xT, float* __restrict__ rowsum,
             float* __restrict__ pctx) {
  int b = blockIdx.y, prow = blockIdx.x, t = threadIdx.x;
  int y = prow - 1;
  __shared__ __align__(16) unsigned short sx[128 * 64];
  __shared__ float swm[128];
  __shared__ float red[4 * 56];
  __shared__ float se[56];
  bool rowvalid = ((unsigned)y < 56u);

  if (!rowvalid) {                       // pad row: zero outputs directly
    unsigned short* dst = xT + (size_t)(b * 58 + prow) * XT_ROW;
    uint4 z4 = make_uint4(0u, 0u, 0u, 0u);
    #pragma unroll
    for (int q = 0; q < 4; q++)
      *reinterpret_cast<uint4*>(dst + (size_t)(t + 256 * q) * 8) = z4;
    if (t == 0) rowsum[b * 58 + prow] = 0.f;
    if (t < 128) pctx[(size_t)(b * 58 + prow) * 128 + t] = 0.f;
    return;
  }

  if (t < 128) swm[t] = w_mask[t];
  // load phase: 1792 float4 chunks, wave-coalesced (chunk = ci*14 + j)
  #pragma unroll
  for (int i = 0; i < 7; i++) {
    int c = t + 256 * i;
    int ci = c / 14, j = c - ci * 14;
    const float4 v = *reinterpret_cast<const float4*>(
        x + (size_t)(b * 128 + ci) * SS + y * 56 + j * 4);
    union { unsigned short s[4]; uint2 u; } pk;
    pk.s[0] = f2bf(v.x); pk.s[1] = f2bf(v.y);
    pk.s[2] = f2bf(v.z); pk.s[3] = f2bf(v.w);
    int blk = j ^ sswz(ci);
    *reinterpret_cast<uint2*>(&sx[ci * 64 + (blk << 2)]) = pk.u;
  }
  __syncthreads();

  // mask partials: thread (g, xx) dots 32 ci against w_mask
  if (t < 224) {
    int xx = t % 56, g = t / 56;
    float acc = 0.f;
    #pragma unroll
    for (int k = 0; k < 32; k++) {
      int ci = g * 32 + k;
      acc += bf2f(sx[ci * 64 + ((((xx >> 2) ^ sswz(ci)) << 2) | (xx & 3))]) * swm[ci];
    }
    red[g * 56 + xx] = acc;
  }
  __syncthreads();

  float e = 0.f;
  if (t < 56) {
    float m = red[t] + red[56 + t] + red[112 + t] + red[168 + t] + b_mask[0];
    e = expf(m);
    se[t] = e;
  }
  if (t < 64) {
    float s = waveReduceSum(e);
    if (t == 0) rowsum[b * 58 + prow] = s;   // 0 on pad rows
  }

  // NHWC write (only needs sx — overlap with exp work, before se-sync)
  {
    int pcol = t >> 2, cig = t & 3;
    int xx = pcol - 1;
    bool colv = ((unsigned)xx < 56u);
    unsigned short tmp[32];
    #pragma unroll
    for (int i = 0; i < 32; i++) {
      int ci = cig * 32 + i;
      tmp[i] = colv ? sx[ci * 64 + ((((xx >> 2) ^ sswz(ci)) << 2) | (xx & 3))]
                    : (unsigned short)0;
    }
    unsigned short* dst = xT + ((size_t)(b * 58 + prow) * 64 + pcol) * 128 + cig * 32;
    #pragma unroll
    for (int q = 0; q < 4; q++)
      *reinterpret_cast<uint4*>(dst + q * 8) = *reinterpret_cast<const uint4*>(tmp + q * 8);
  }
  __syncthreads();   // se ready

  // context partials: thread (c = t>>1, h = t&1) does 28 MACs, pair-combine
  {
    int c = t >> 1, h = t & 1;
    float acc = 0.f;
    #pragma unroll
    for (int j = 0; j < 28; j++) {
      int col = h * 28 + j;
      acc += bf2f(sx[c * 64 + ((((col >> 2) ^ sswz(c)) << 2) | (col & 3))]) * se[col];
    }
    acc += __shfl_xor(acc, 1, 64);
    if (h == 0) pctx[(size_t)(b * 58 + prow) * 128 + c] = acc;
  }
}

// K4: per-sample ctx finish + bottleneck MLP + sigmoid, computed ONCE per b.
// Output a[b][256] stored in-place over the first 256 floats of pctx[b]'s own
// region (dead after the reduction here; thread t writes exactly the elements
// only it read). grid(16), 128 threads.
__global__ void k4_mlp(const float* __restrict__ rowsum, float* __restrict__ pctx,
                       const float* __restrict__ w1, const float* __restrict__ b1,
                       const float* __restrict__ ln_g, const float* __restrict__ ln_b,
                       const float* __restrict__ w2, const float* __restrict__ b2) {
  int b = blockIdx.x, t = threadIdx.x;
  __shared__ float sc[128], st[16], sn[16], shz;
  float rv = (t < 58) ? rowsum[b * 58 + t] : 0.f;
  float acc = 0.f;
  #pragma unroll
  for (int r = 0; r < 58; r++) acc += pctx[(size_t)(b * 58 + r) * 128 + t];
  if (t < 64) {
    float z = waveReduceSum(rv);
    if (t == 0) shz = 1.0f / z;
  }
  __syncthreads();
  sc[t] = acc * shz;
  __syncthreads();
  // stage 1: t = ctx @ w1^T + b1
  if (t < 16) {
    float s = b1[t];
    #pragma unroll 8
    for (int c = 0; c < 128; c++) s += sc[c] * w1[t * 128 + c];
    st[t] = s;
  }
  __syncthreads();
  // LayerNorm + ReLU
  if (t < 16) {
    float mu = 0.f, m2 = 0.f;
    #pragma unroll
    for (int r = 0; r < 16; r++) { float v = st[r]; mu += v; m2 += v * v; }
    mu *= (1.f / 16.f); m2 *= (1.f / 16.f);
    float rstd = rsqrtf(m2 - mu * mu + 1e-5f);
    float v = (st[t] - mu) * rstd * ln_g[t] + ln_b[t];
    sn[t] = fmaxf(v, 0.f);
  }
  __syncthreads();
  // stage 2: 256 sigmoid outputs, 2 per thread, written over pctx[b][0:256)
  #pragma unroll
  for (int k = 0; k < 2; k++) {
    int mo = t + 128 * k;
    float s = b2[mo];
    #pragma unroll
    for (int r = 0; r < 16; r++) s += sn[r] * w2[mo * 16 + r];
    pctx[(size_t)b * (58 * 128) + mo] = 1.f / (1.f + expf(-s));
  }
}

// K5: weight generation only. e = ci*9 + khw, so thread `ci` owns a CONTIGUOUS
// 36 B strip of w_fc/b_fc (no div/mod). Scale, bf16-cast, scatter 9 shorts into
// an LDS bounce buffer at the swizzled positions (bijective within each
// 64-short block -> conflict-free), then store rows as coalesced uint4.
// grid(co=128, bp=8), 256 threads: (ci = t&127, bb = t>>7), b = bp*2 + bb.
// FIX vs round 1: store loop covers all 288 uint4 chunks (was 144 -> half of
// every weight row left as stale garbage).
__global__ void k5_wgen(const float* __restrict__ w_fc, const float* __restrict__ b_fc,
                        const float* __restrict__ abuf, unsigned short* __restrict__ wd) {
  int co = blockIdx.x, bp = blockIdx.y, t = threadIdx.x;
  int ci = t & 127, bb = t >> 7, b = bp * 2 + bb;
  __shared__ unsigned short sw[2][1152];
  const float* wr = w_fc + co * 1152 + ci * 9;
  const float* br = b_fc + co * 1152 + ci * 9;
  float a = abuf[(size_t)b * (58 * 128) + 2 * co + (ci >> 6)];
  int kq = ci & 63;
  int pos = (((kq >> 3) ^ (co & 7)) << 3) | (kq & 7);
  int kb0 = ci >> 6;
  #pragma unroll
  for (int khw = 0; khw < 9; khw++) {
    float v = a * wr[khw] + br[khw];
    sw[bb][(khw * 2 + kb0) * 64 + pos] = f2bf(v);
  }
  __syncthreads();
  // 2 rows x 144 uint4 chunks = 288 chunks, grid-stride over 256 threads
  for (int c = t; c < 288; c += 256) {
    int row = c / 144, q = c - row * 144;
    unsigned short* dst = wd + (size_t)((bp * 2 + row) * 128 + co) * 1152 + q * 8;
    *reinterpret_cast<uint4*>(dst) = *reinterpret_cast<const uint4*>(&sw[row][q * 8]);
  }
}

// K6: implicit-GEMM conv, 512 threads, tile 128co x 128s (2 out rows),
// both operands staged via global_load_lds (A: pre-swizzled weight rows,
// B: NHWC rows with source-permuted XOR swizzle). acc[4][2] per wave.
// (UNCHANGED — frozen for attribution; dbuf variant regressed previously.)
__global__ __launch_bounds__(512, 4) void k6_conv(const unsigned short* __restrict__ xT,
                                                  const unsigned short* __restrict__ wd,
                                                  float* __restrict__ out) {
  __shared__ __align__(16) unsigned short As[8192];   // [co128][kq64]
  __shared__ __align__(16) unsigned short Bs[8192];   // [s128][kq64]
  int t = threadIdx.x;
  int b = blockIdx.y, y0 = blockIdx.x * 2;
  int wave = t >> 6, lane = t & 63, l15 = lane & 15, quad = lane >> 4;
  int x7 = lane & 7;
  const unsigned short* wp  = wd + (size_t)b * (128 * 1152);
  const unsigned short* xTb = xT + (size_t)b * XT_PER_B;

  int ch0 = wave * 128 + lane, ch1 = ch0 + 64;
  int offA0 = (ch0 >> 3) * 1152 + (ch0 & 7) * 8;      // + kb*64 per step
  int offA1 = (ch1 >> 3) * 1152 + (ch1 & 7) * 8;
  int s0 = ch0 >> 3, s1 = ch1 >> 3;
  int c_ = lane & 7;
  int sr0 = s0 / 56, sc0 = s0 - sr0 * 56; if (sr0 >= 2) { sr0 = 0; sc0 = 0; }
  int sr1 = s1 / 56, sc1 = s1 - sr1 * 56; if (sr1 >= 2) { sr1 = 0; sc1 = 0; }
  int offB0 = (y0 + sr0) * XT_ROW + sc0 * 128 + (c_ ^ (s0 & 7)) * 8;
  int offB1 = (y0 + sr1) * XT_ROW + sc1 * 128 + (c_ ^ (s1 & 7)) * 8;
  unsigned short* dA0 = &As[wave * 1024];
  unsigned short* dA1 = &As[wave * 1024 + 512];
  unsigned short* dB0 = &Bs[wave * 1024];
  unsigned short* dB1 = &Bs[wave * 1024 + 512];

  int s_base = (wave & 3) * 32;
  int co_b   = (wave >> 2) * 64;

  floatx4 acc[4][2];
  floatx4 zero = {0.f, 0.f, 0.f, 0.f};
  #pragma unroll
  for (int i = 0; i < 4; i++)
    #pragma unroll
    for (int j = 0; j < 2; j++) acc[i][j] = zero;

  for (int kb = 0; kb < NKB; kb++) {
    int khw = kb >> 1;
    int kh = khw / 3;
    int kw = khw - kh * 3;
    int dB = kh * XT_ROW + kw * 128 + ((kb & 1) << 6);
    int dA = kb * 64;
    __syncthreads();                      // prior frag reads complete
    load_lds16(wp + offA0 + dA, dA0);
    load_lds16(wp + offA1 + dA, dA1);
    load_lds16(xTb + offB0 + dB, dB0);
    load_lds16(xTb + offB1 + dB, dB1);
    __syncthreads();                      // DMA drained (vmcnt(0) at barrier)
    #pragma unroll
    for (int kk = 0; kk < 2; kk++) {
      bf16x8 af[4], bfr[2];
      int pc = ((kk * 4 + quad) ^ x7) << 3;
      #pragma unroll
      for (int i = 0; i < 4; i++)
        af[i] = *reinterpret_cast<const bf16x8*>(&As[(co_b + i * 16 + l15) * 64 + pc]);
      #pragma unroll
      for (int j = 0; j < 2; j++)
        bfr[j] = *reinterpret_cast<const bf16x8*>(&Bs[(s_base + j * 16 + l15) * 64 + pc]);
      #pragma unroll
      for (int i = 0; i < 4; i++)
        #pragma unroll
        for (int j = 0; j < 2; j++)
          acc[i][j] = __builtin_amdgcn_mfma_f32_16x16x32_bf16(af[i], bfr[j], acc[i][j], 0, 0, 0);
    }
  }

  // epilogue: D col (l15) -> s, row (quad*4+r) -> co
  float* ob = out + (size_t)b * COUT * SS + y0 * 56;
  #pragma unroll
  for (int i = 0; i < 4; i++) {
    #pragma unroll
    for (int j = 0; j < 2; j++) {
      int sl = s_base + j * 16 + l15;
      if (sl < 112) {
        int row = (sl >= 56) ? 1 : 0;
        int col = sl - row * 56;
        #pragma unroll
        for (int r = 0; r < 4; r++) {
          int co = co_b + i * 16 + quad * 4 + r;
          ob[(size_t)co * SS + row * 56 + col] = acc[i][j][r];
        }
      }
    }
  }
}

extern "C" void kernel_launch(void* const* d_in, const int* in_sizes, int n_in,
                              void* d_out, int out_size, void* d_ws, size_t ws_size,
                              hipStream_t stream) {
  const float* x      = (const float*)d_in[0];
  const float* w_mask = (const float*)d_in[1];
  const float* b_mask = (const float*)d_in[2];
  const float* w1     = (const float*)d_in[3];
  const float* b1     = (const float*)d_in[4];
  const float* ln_g   = (const float*)d_in[5];
  const float* ln_b   = (const float*)d_in[6];
  const float* w2     = (const float*)d_in[7];
  const float* b2     = (const float*)d_in[8];
  const float* w_fc   = (const float*)d_in[9];
  const float* b_fc   = (const float*)d_in[10];
  float* out = (float*)d_out;

  char* ws = (char*)d_ws;
  unsigned short* xT  = (unsigned short*)(ws);               // 15,204,352 B
  unsigned short* wdw = (unsigned short*)(ws + 15204352);    //  4,718,592 B
  float* rowsum = (float*)(ws + 19922944);                   //      3,712 B
  float* pctx   = (float*)(ws + 19927040);                   //    475,136 B

  k0_padT<<<dim3(58, 16),  dim3(256), 0, stream>>>(x, w_mask, b_mask, xT, rowsum, pctx);
  k4_mlp <<<dim3(16),      dim3(128), 0, stream>>>(rowsum, pctx, w1, b1, ln_g, ln_b, w2, b2);
  k5_wgen<<<dim3(128, 8),  dim3(256), 0, stream>>>(w_fc, b_fc, pctx, wdw);
  k6_conv<<<dim3(28, 16),  dim3(512), 0, stream>>>(xT, wdw, out);
}

// Round 3
// 132.726 us; speedup vs baseline: 1.0148x; 1.0002x over previous
//
#include <hip/hip_runtime.h>
#include <hip/hip_bf16.h>
#include <math.h>

// ---- problem constants ----
#define BATCH 16
#define CIN   128
#define COUT  128
#define SS    3136          // 56*56
#define XT_ROW 8192         // shorts per padded row: 64 pcol * 128 ci
#define XT_PER_B (58*XT_ROW)
#define NKB   18

typedef __attribute__((ext_vector_type(8))) __bf16 bf16x8;
typedef __attribute__((ext_vector_type(4))) float  floatx4;

static __device__ __forceinline__ unsigned short f2bf(float f) {
  union { float f; unsigned u; } v; v.f = f;
  unsigned r = v.u + 0x7fffu + ((v.u >> 16) & 1u);   // RNE
  return (unsigned short)(r >> 16);
}
static __device__ __forceinline__ float bf2f(unsigned short u) {
  union { unsigned u; float f; } v; v.u = ((unsigned)u) << 16; return v.f;
}

static __device__ __forceinline__ float waveReduceSum(float v) {
  #pragma unroll
  for (int off = 32; off > 0; off >>= 1) v += __shfl_xor(v, off, 64);
  return v;
}

static __device__ __forceinline__ void load_lds16(const void* g, void* l) {
  __builtin_amdgcn_global_load_lds(
      (const __attribute__((address_space(1))) void*)g,
      (__attribute__((address_space(3))) void*)l, 16, 0, 0);
}

// Raw barrier fenced on BOTH sides: llvm.amdgcn.s.barrier is IntrNoMem, so
// without the asm memory clobbers the scheduler may move LDS reads above it
// (racing other waves' DMA fills) or DMA issues below it (racing readers).
static __device__ __forceinline__ void barrier_fenced() {
  asm volatile("" ::: "memory");
  __builtin_amdgcn_s_barrier();
  asm volatile("" ::: "memory");
}

// LDS column-block swizzle: spreads banks across ci for transpose reads
static __device__ __forceinline__ int sswz(int ci) {
  return (ci ^ (ci >> 4)) & 15;
}

// K0: fused pad+transpose to NHWC bf16 + attention mask row + exp + per-row
// context partials. (FROZEN — unchanged from round 2, passing.)
__global__ __launch_bounds__(256, 4)
void k0_padT(const float* __restrict__ x, const float* __restrict__ w_mask,
             const float* __restrict__ b_mask,
             unsigned short* __restrict__ xT, float* __restrict__ rowsum,
             float* __restrict__ pctx) {
  int b = blockIdx.y, prow = blockIdx.x, t = threadIdx.x;
  int y = prow - 1;
  __shared__ __align__(16) unsigned short sx[128 * 64];
  __shared__ float swm[128];
  __shared__ float red[4 * 56];
  __shared__ float se[56];
  bool rowvalid = ((unsigned)y < 56u);

  if (!rowvalid) {                       // pad row: zero outputs directly
    unsigned short* dst = xT + (size_t)(b * 58 + prow) * XT_ROW;
    uint4 z4 = make_uint4(0u, 0u, 0u, 0u);
    #pragma unroll
    for (int q = 0; q < 4; q++)
      *reinterpret_cast<uint4*>(dst + (size_t)(t + 256 * q) * 8) = z4;
    if (t == 0) rowsum[b * 58 + prow] = 0.f;
    if (t < 128) pctx[(size_t)(b * 58 + prow) * 128 + t] = 0.f;
    return;
  }

  if (t < 128) swm[t] = w_mask[t];
  // load phase: 1792 float4 chunks, wave-coalesced (chunk = ci*14 + j)
  #pragma unroll
  for (int i = 0; i < 7; i++) {
    int c = t + 256 * i;
    int ci = c / 14, j = c - ci * 14;
    const float4 v = *reinterpret_cast<const float4*>(
        x + (size_t)(b * 128 + ci) * SS + y * 56 + j * 4);
    union { unsigned short s[4]; uint2 u; } pk;
    pk.s[0] = f2bf(v.x); pk.s[1] = f2bf(v.y);
    pk.s[2] = f2bf(v.z); pk.s[3] = f2bf(v.w);
    int blk = j ^ sswz(ci);
    *reinterpret_cast<uint2*>(&sx[ci * 64 + (blk << 2)]) = pk.u;
  }
  __syncthreads();

  // mask partials: thread (g, xx) dots 32 ci against w_mask
  if (t < 224) {
    int xx = t % 56, g = t / 56;
    float acc = 0.f;
    #pragma unroll
    for (int k = 0; k < 32; k++) {
      int ci = g * 32 + k;
      acc += bf2f(sx[ci * 64 + ((((xx >> 2) ^ sswz(ci)) << 2) | (xx & 3))]) * swm[ci];
    }
    red[g * 56 + xx] = acc;
  }
  __syncthreads();

  float e = 0.f;
  if (t < 56) {
    float m = red[t] + red[56 + t] + red[112 + t] + red[168 + t] + b_mask[0];
    e = expf(m);
    se[t] = e;
  }
  if (t < 64) {
    float s = waveReduceSum(e);
    if (t == 0) rowsum[b * 58 + prow] = s;   // 0 on pad rows
  }

  // NHWC write (only needs sx — overlap with exp work, before se-sync)
  {
    int pcol = t >> 2, cig = t & 3;
    int xx = pcol - 1;
    bool colv = ((unsigned)xx < 56u);
    unsigned short tmp[32];
    #pragma unroll
    for (int i = 0; i < 32; i++) {
      int ci = cig * 32 + i;
      tmp[i] = colv ? sx[ci * 64 + ((((xx >> 2) ^ sswz(ci)) << 2) | (xx & 3))]
                    : (unsigned short)0;
    }
    unsigned short* dst = xT + ((size_t)(b * 58 + prow) * 64 + pcol) * 128 + cig * 32;
    #pragma unroll
    for (int q = 0; q < 4; q++)
      *reinterpret_cast<uint4*>(dst + q * 8) = *reinterpret_cast<const uint4*>(tmp + q * 8);
  }
  __syncthreads();   // se ready

  // context partials: thread (c = t>>1, h = t&1) does 28 MACs, pair-combine
  {
    int c = t >> 1, h = t & 1;
    float acc = 0.f;
    #pragma unroll
    for (int j = 0; j < 28; j++) {
      int col = h * 28 + j;
      acc += bf2f(sx[c * 64 + ((((col >> 2) ^ sswz(c)) << 2) | (col & 3))]) * se[col];
    }
    acc += __shfl_xor(acc, 1, 64);
    if (h == 0) pctx[(size_t)(b * 58 + prow) * 128 + c] = acc;
  }
}

// K4: per-sample ctx finish + bottleneck MLP + sigmoid. (FROZEN.)
__global__ void k4_mlp(const float* __restrict__ rowsum, float* __restrict__ pctx,
                       const float* __restrict__ w1, const float* __restrict__ b1,
                       const float* __restrict__ ln_g, const float* __restrict__ ln_b,
                       const float* __restrict__ w2, const float* __restrict__ b2) {
  int b = blockIdx.x, t = threadIdx.x;
  __shared__ float sc[128], st[16], sn[16], shz;
  float rv = (t < 58) ? rowsum[b * 58 + t] : 0.f;
  float acc = 0.f;
  #pragma unroll
  for (int r = 0; r < 58; r++) acc += pctx[(size_t)(b * 58 + r) * 128 + t];
  if (t < 64) {
    float z = waveReduceSum(rv);
    if (t == 0) shz = 1.0f / z;
  }
  __syncthreads();
  sc[t] = acc * shz;
  __syncthreads();
  if (t < 16) {
    float s = b1[t];
    #pragma unroll 8
    for (int c = 0; c < 128; c++) s += sc[c] * w1[t * 128 + c];
    st[t] = s;
  }
  __syncthreads();
  if (t < 16) {
    float mu = 0.f, m2 = 0.f;
    #pragma unroll
    for (int r = 0; r < 16; r++) { float v = st[r]; mu += v; m2 += v * v; }
    mu *= (1.f / 16.f); m2 *= (1.f / 16.f);
    float rstd = rsqrtf(m2 - mu * mu + 1e-5f);
    float v = (st[t] - mu) * rstd * ln_g[t] + ln_b[t];
    sn[t] = fmaxf(v, 0.f);
  }
  __syncthreads();
  #pragma unroll
  for (int k = 0; k < 2; k++) {
    int mo = t + 128 * k;
    float s = b2[mo];
    #pragma unroll
    for (int r = 0; r < 16; r++) s += sn[r] * w2[mo * 16 + r];
    pctx[(size_t)b * (58 * 128) + mo] = 1.f / (1.f + expf(-s));
  }
}

// K5: weight generation only. (FROZEN — round-2 fixed version, passing.)
__global__ void k5_wgen(const float* __restrict__ w_fc, const float* __restrict__ b_fc,
                        const float* __restrict__ abuf, unsigned short* __restrict__ wd) {
  int co = blockIdx.x, bp = blockIdx.y, t = threadIdx.x;
  int ci = t & 127, bb = t >> 7, b = bp * 2 + bb;
  __shared__ unsigned short sw[2][1152];
  const float* wr = w_fc + co * 1152 + ci * 9;
  const float* br = b_fc + co * 1152 + ci * 9;
  float a = abuf[(size_t)b * (58 * 128) + 2 * co + (ci >> 6)];
  int kq = ci & 63;
  int pos = (((kq >> 3) ^ (co & 7)) << 3) | (kq & 7);
  int kb0 = ci >> 6;
  #pragma unroll
  for (int khw = 0; khw < 9; khw++) {
    float v = a * wr[khw] + br[khw];
    sw[bb][(khw * 2 + kb0) * 64 + pos] = f2bf(v);
  }
  __syncthreads();
  for (int c = t; c < 288; c += 256) {
    int row = c / 144, q = c - row * 144;
    unsigned short* dst = wd + (size_t)((bp * 2 + row) * 128 + co) * 1152 + q * 8;
    *reinterpret_cast<uint4*>(dst) = *reinterpret_cast<const uint4*>(&sw[row][q * 8]);
  }
}

// K6: implicit-GEMM conv, 512 threads, tile 128co x 128s. REWRITTEN this
// round: double-buffered LDS + counted vmcnt(4) (T3/T4 minimum) + setprio.
// Old structure drained vmcnt(0) BEFORE every MFMA phase (zero overlap);
// now batch kb+1's 4 global_load_lds stay in flight across the barrier and
// land under batch kb's MFMA work. Never drains to 0 mid-loop.
__global__ __launch_bounds__(512, 4) void k6_conv(const unsigned short* __restrict__ xT,
                                                  const unsigned short* __restrict__ wd,
                                                  float* __restrict__ out) {
  __shared__ __align__(16) unsigned short As[2][8192];   // [dbuf][co128][kq64]
  __shared__ __align__(16) unsigned short Bs[2][8192];   // [dbuf][s128][kq64]
  int t = threadIdx.x;
  int b = blockIdx.y, y0 = blockIdx.x * 2;
  int wave = t >> 6, lane = t & 63, l15 = lane & 15, quad = lane >> 4;
  int x7 = lane & 7;
  const unsigned short* wp  = wd + (size_t)b * (128 * 1152);
  const unsigned short* xTb = xT + (size_t)b * XT_PER_B;

  // DMA chunk ids (16B units): this thread covers ch0, ch1 of 1024
  int ch0 = wave * 128 + lane, ch1 = ch0 + 64;
  int offA0 = (ch0 >> 3) * 1152 + (ch0 & 7) * 8;      // + kb*64 per step
  int offA1 = (ch1 >> 3) * 1152 + (ch1 & 7) * 8;
  int s0 = ch0 >> 3, s1 = ch1 >> 3;
  int c_ = lane & 7;
  int sr0 = s0 / 56, sc0 = s0 - sr0 * 56; if (sr0 >= 2) { sr0 = 0; sc0 = 0; }
  int sr1 = s1 / 56, sc1 = s1 - sr1 * 56; if (sr1 >= 2) { sr1 = 0; sc1 = 0; }
  int offB0 = (y0 + sr0) * XT_ROW + sc0 * 128 + (c_ ^ (s0 & 7)) * 8;
  int offB1 = (y0 + sr1) * XT_ROW + sc1 * 128 + (c_ ^ (s1 & 7)) * 8;

  int s_base = (wave & 3) * 32;
  int co_b   = (wave >> 2) * 64;

  floatx4 acc[4][2];
  floatx4 zero = {0.f, 0.f, 0.f, 0.f};
  #pragma unroll
  for (int i = 0; i < 4; i++)
    #pragma unroll
    for (int j = 0; j < 2; j++) acc[i][j] = zero;

  auto stage = [&](int buf, int kb) {
    int khw = kb >> 1;
    int kh = khw / 3;
    int kw = khw - kh * 3;
    int dB = kh * XT_ROW + kw * 128 + ((kb & 1) << 6);
    int dA = kb * 64;
    load_lds16(wp + offA0 + dA, &As[buf][wave * 1024]);
    load_lds16(wp + offA1 + dA, &As[buf][wave * 1024 + 512]);
    load_lds16(xTb + offB0 + dB, &Bs[buf][wave * 1024]);
    load_lds16(xTb + offB1 + dB, &Bs[buf][wave * 1024 + 512]);
  };

  stage(0, 0);                            // 4 loads in flight
  for (int kb = 0; kb < NKB; kb++) {
    int cur = kb & 1;
    if (kb + 1 < NKB) {
      stage(cur ^ 1, kb + 1);             // 8 in flight
      asm volatile("s_waitcnt vmcnt(4)" ::: "memory");   // batch kb landed
    } else {
      asm volatile("s_waitcnt vmcnt(0)" ::: "memory");   // last batch
    }
    barrier_fenced();                     // buf[cur] ready for ALL waves
    __builtin_amdgcn_s_setprio(1);
    #pragma unroll
    for (int kk = 0; kk < 2; kk++) {
      bf16x8 af[4], bfr[2];
      int pc = ((kk * 4 + quad) ^ x7) << 3;
      #pragma unroll
      for (int i = 0; i < 4; i++)
        af[i] = *reinterpret_cast<const bf16x8*>(&As[cur][(co_b + i * 16 + l15) * 64 + pc]);
      #pragma unroll
      for (int j = 0; j < 2; j++)
        bfr[j] = *reinterpret_cast<const bf16x8*>(&Bs[cur][(s_base + j * 16 + l15) * 64 + pc]);
      #pragma unroll
      for (int i = 0; i < 4; i++)
        #pragma unroll
        for (int j = 0; j < 2; j++)
          acc[i][j] = __builtin_amdgcn_mfma_f32_16x16x32_bf16(af[i], bfr[j], acc[i][j], 0, 0, 0);
    }
    __builtin_amdgcn_s_setprio(0);
    barrier_fenced();                     // all waves done reading buf[cur]
  }

  // epilogue: D col (l15) -> s, row (quad*4+r) -> co
  float* ob = out + (size_t)b * COUT * SS + y0 * 56;
  #pragma unroll
  for (int i = 0; i < 4; i++) {
    #pragma unroll
    for (int j = 0; j < 2; j++) {
      int sl = s_base + j * 16 + l15;
      if (sl < 112) {
        int row = (sl >= 56) ? 1 : 0;
        int col = sl - row * 56;
        #pragma unroll
        for (int r = 0; r < 4; r++) {
          int co = co_b + i * 16 + quad * 4 + r;
          ob[(size_t)co * SS + row * 56 + col] = acc[i][j][r];
        }
      }
    }
  }
}

extern "C" void kernel_launch(void* const* d_in, const int* in_sizes, int n_in,
                              void* d_out, int out_size, void* d_ws, size_t ws_size,
                              hipStream_t stream) {
  const float* x      = (const float*)d_in[0];
  const float* w_mask = (const float*)d_in[1];
  const float* b_mask = (const float*)d_in[2];
  const float* w1     = (const float*)d_in[3];
  const float* b1     = (const float*)d_in[4];
  const float* ln_g   = (const float*)d_in[5];
  const float* ln_b   = (const float*)d_in[6];
  const float* w2     = (const float*)d_in[7];
  const float* b2     = (const float*)d_in[8];
  const float* w_fc   = (const float*)d_in[9];
  const float* b_fc   = (const float*)d_in[10];
  float* out = (float*)d_out;

  char* ws = (char*)d_ws;
  unsigned short* xT  = (unsigned short*)(ws);               // 15,204,352 B
  unsigned short* wdw = (unsigned short*)(ws + 15204352);    //  4,718,592 B
  float* rowsum = (float*)(ws + 19922944);                   //      3,712 B
  float* pctx   = (float*)(ws + 19927040);                   //    475,136 B

  k0_padT<<<dim3(58, 16),  dim3(256), 0, stream>>>(x, w_mask, b_mask, xT, rowsum, pctx);
  k4_mlp <<<dim3(16),      dim3(128), 0, stream>>>(rowsum, pctx, w1, b1, ln_g, ln_b, w2, b2);
  k5_wgen<<<dim3(128, 8),  dim3(256), 0, stream>>>(w_fc, b_fc, pctx, wdw);
  k6_conv<<<dim3(28, 16),  dim3(512), 0, stream>>>(xT, wdw, out);
}